// Round 2
// baseline (370.047 us; speedup 1.0000x reference)
//
#include <hip/hip_runtime.h>
#include <hip/hip_bf16.h>
#include <cstdint>
#include <cstddef>

// ---------------------------------------------------------------------------
// bi_Mlp (fp32 I/O): out = binlin2( clip(gelu(binlin1(x))) )
//   binlin(w) x = (alpha * sign(w)) x + b, alpha = mean|w| per out-channel.
// Plan: prep fp32 w -> {fp32 alpha, bf16 sign(+-1)}, fp32 x -> bf16,
// then two m97-style 128x128 bf16-MFMA GEMMs, fp32 epilogue (alpha, bias,
// exact-erf gelu + clip for GEMM1), fp32 final store.
// ---------------------------------------------------------------------------

typedef __bf16 bf16x8 __attribute__((ext_vector_type(8)));
typedef __bf16 bf16x4 __attribute__((ext_vector_type(4)));
typedef float floatx4 __attribute__((ext_vector_type(4)));

__device__ __forceinline__ void async_load16(const void* g, void* l) {
    __builtin_amdgcn_global_load_lds(
        (const __attribute__((address_space(1))) void*)g,
        (__attribute__((address_space(3))) void*)l,
        16, 0, 0);
}

// fp32 -> bf16 conversion, 4 elems/thread (n divisible by 1024 per launch calc)
__global__ __launch_bounds__(256) void x_to_bf16(
    const float* __restrict__ in, __hip_bfloat16* __restrict__ out, int n4)
{
    int i = blockIdx.x * 256 + threadIdx.x;
    if (i < n4) {
        float4 v = ((const float4*)in)[i];
        bf16x4 o;
        o[0] = (__bf16)v.x; o[1] = (__bf16)v.y;
        o[2] = (__bf16)v.z; o[3] = (__bf16)v.w;
        ((bf16x4*)out)[i] = o;
    }
}

// One block per row of W[rows, cols] (fp32): alpha[row] = mean|W[row,:]|,
// sgn[row,:] = sign(W) as exact bf16 (+1/-1/0).
__global__ __launch_bounds__(256) void bin_prep(
    const float* __restrict__ w,
    __hip_bfloat16* __restrict__ sgn,
    float* __restrict__ alpha,
    int cols)
{
    const int row = blockIdx.x;
    const float* wr = w + (size_t)row * cols;
    __hip_bfloat16* sr = sgn + (size_t)row * cols;
    float s = 0.0f;
    for (int c = threadIdx.x; c < cols; c += 256) {
        float v = wr[c];
        s += fabsf(v);
        sr[c] = __float2bfloat16(v > 0.0f ? 1.0f : (v < 0.0f ? -1.0f : 0.0f));
    }
    #pragma unroll
    for (int off = 32; off > 0; off >>= 1) s += __shfl_down(s, off, 64);
    __shared__ float wsum[4];
    const int lane = threadIdx.x & 63;
    const int wv = threadIdx.x >> 6;
    if (lane == 0) wsum[wv] = s;
    __syncthreads();
    if (threadIdx.x == 0) {
        float t = wsum[0] + wsum[1] + wsum[2] + wsum[3];
        alpha[row] = t / (float)cols;
    }
}

#define TILE_M 128
#define TILE_N 128
#define TILE_K 64

__device__ __forceinline__ void store_val(__hip_bfloat16* C, size_t idx, float v) {
    C[idx] = __float2bfloat16(v);
}
__device__ __forceinline__ void store_val(float* C, size_t idx, float v) {
    C[idx] = v;
}

// C[M,N] = (A[M,K] . S[N,K]^T) * alpha[N] + bias[N]  (+ optional gelu/clip)
// A, S bf16; alpha, bias fp32; C is bf16 or fp32 per OutT.
template <bool DO_GELU, typename OutT>
__global__ __launch_bounds__(256) void gemm_bin(
    const __hip_bfloat16* __restrict__ A,
    const __hip_bfloat16* __restrict__ S,
    const float* __restrict__ alpha,
    const float* __restrict__ bias,
    OutT* __restrict__ C,
    int M, int N, int K)
{
    __shared__ __align__(16) __hip_bfloat16 sA[TILE_M * TILE_K];
    __shared__ __align__(16) __hip_bfloat16 sB[TILE_N * TILE_K];

    const int tid = threadIdx.x;
    const int wave = tid >> 6;
    const int lane = tid & 63;
    const int bm = blockIdx.y * TILE_M;
    const int bn = blockIdx.x * TILE_N;

    // wave -> 64x64 quadrant; lane -> mfma fragment coords
    const int wm = (wave & 1) * 64;
    const int wn = (wave >> 1) * 64;
    const int lr = lane & 15;         // m (A) / n (B) index within 16-tile
    const int lk = (lane >> 4) * 8;   // k offset within 32-step

    // staging coords: each lane fetches one 16B chunk (8 bf16); lane order
    // matches the wave-uniform-base + lane*16 LDS write pattern.
    const int crow = lane >> 3;       // 0..7 row within 8-row segment
    const int ccol = (lane & 7) * 8;  // element column within 64-wide tile

    floatx4 acc[4][4];
    #pragma unroll
    for (int i = 0; i < 4; i++)
        #pragma unroll
        for (int j = 0; j < 4; j++)
            #pragma unroll
            for (int r = 0; r < 4; r++)
                acc[i][j][r] = 0.0f;

    for (int k0 = 0; k0 < K; k0 += TILE_K) {
        // --- stage A and B tiles (global -> LDS, 16B/lane, wave-uniform dst)
        #pragma unroll
        for (int j = 0; j < 4; j++) {
            const int seg = wave * 4 + j;        // 0..15, 8 rows each
            const int r = seg * 8 + crow;        // 0..127
            int ar = bm + r;
            ar = ar < M ? ar : (M - 1);          // clamp tail rows (stores guarded)
            async_load16(A + (size_t)ar * K + (k0 + ccol), (void*)(sA + seg * 512));
            async_load16(S + (size_t)(bn + r) * K + (k0 + ccol), (void*)(sB + seg * 512));
        }
        __syncthreads();  // compiler drains vmcnt before barrier

        // --- compute: 2 k-steps of 32, 16 MFMAs each
        #pragma unroll
        for (int ks = 0; ks < 2; ks++) {
            bf16x8 af[4], bfv[4];
            #pragma unroll
            for (int i = 0; i < 4; i++)
                af[i] = *(const bf16x8*)(sA + (wm + i * 16 + lr) * TILE_K + ks * 32 + lk);
            #pragma unroll
            for (int j = 0; j < 4; j++)
                bfv[j] = *(const bf16x8*)(sB + (wn + j * 16 + lr) * TILE_K + ks * 32 + lk);
            #pragma unroll
            for (int i = 0; i < 4; i++)
                #pragma unroll
                for (int j = 0; j < 4; j++)
                    acc[i][j] = __builtin_amdgcn_mfma_f32_16x16x32_bf16(
                        af[i], bfv[j], acc[i][j], 0, 0, 0);
        }
        __syncthreads();
    }

    // --- epilogue: alpha/bias in fp32, optional exact-erf gelu + clip
    float al[4], bi[4];
    #pragma unroll
    for (int j = 0; j < 4; j++) {
        const int col = bn + wn + j * 16 + lr;
        al[j] = alpha[col];
        bi[j] = bias[col];
    }
    #pragma unroll
    for (int i = 0; i < 4; i++) {
        const int row0 = bm + wm + i * 16 + (lane >> 4) * 4;
        #pragma unroll
        for (int r = 0; r < 4; r++) {
            const int row = row0 + r;
            if (row < M) {
                #pragma unroll
                for (int j = 0; j < 4; j++) {
                    float v = acc[i][j][r] * al[j] + bi[j];
                    if (DO_GELU) {
                        v = 0.5f * v * (1.0f + erff(v * 0.70710678118654752f));
                        v = fminf(fmaxf(v, -10.0f), 10.0f);
                    }
                    store_val(C, (size_t)row * N + (bn + wn + j * 16 + lr), v);
                }
            }
        }
    }
}

extern "C" void kernel_launch(void* const* d_in, const int* in_sizes, int n_in,
                              void* d_out, int out_size, void* d_ws, size_t ws_size,
                              hipStream_t stream) {
    const float* x  = (const float*)d_in[0];
    const float* w1 = (const float*)d_in[1];
    const float* b1 = (const float*)d_in[2];
    const float* w2 = (const float*)d_in[3];
    const float* b2 = (const float*)d_in[4];

    const int M = 64 * 197;   // 12608
    const int Cd = 768;
    const int Hd = 3072;

    // workspace layout (~106 MB total)
    char* ws = (char*)d_ws;
    __hip_bfloat16* xb   = (__hip_bfloat16*)ws;                 // [M, Cd]
    __hip_bfloat16* sgn1 = xb + (size_t)M * Cd;                 // [Hd, Cd]
    __hip_bfloat16* sgn2 = sgn1 + (size_t)Hd * Cd;              // [Cd, Hd]
    float* alpha1 = (float*)(sgn2 + (size_t)Cd * Hd);           // [Hd]
    float* alpha2 = alpha1 + Hd;                                // [Cd]
    __hip_bfloat16* hbuf = (__hip_bfloat16*)(alpha2 + Cd);      // [M, Hd]

    const int n4 = (M * Cd) / 4;   // 2420736, divides evenly by 256
    x_to_bf16<<<(n4 + 255) / 256, 256, 0, stream>>>(x, xb, n4);
    bin_prep<<<Hd, 256, 0, stream>>>(w1, sgn1, alpha1, Cd);
    bin_prep<<<Cd, 256, 0, stream>>>(w2, sgn2, alpha2, Hd);

    const int gm = (M + TILE_M - 1) / TILE_M;  // 99
    gemm_bin<true,  __hip_bfloat16><<<dim3(Hd / TILE_N, gm), 256, 0, stream>>>(
        xb, sgn1, alpha1, b1, hbuf, M, Hd, Cd);
    gemm_bin<false, float><<<dim3(Cd / TILE_N, gm), 256, 0, stream>>>(
        hbuf, sgn2, alpha2, b2, (float*)d_out, M, Cd, Hd);
}

// Round 3
// 282.994 us; speedup vs baseline: 1.3076x; 1.3076x over previous
//
#include <hip/hip_runtime.h>
#include <hip/hip_bf16.h>
#include <cstdint>
#include <cstddef>

// ---------------------------------------------------------------------------
// bi_Mlp (fp32 I/O): out = binlin2( clip(gelu(binlin1(x))) )
//   binlin(w) x = (alpha * sign(w)) x + b, alpha = mean|w| per out-channel.
// R2 -> R3: XOR-swizzled LDS layout (slot s of row r holds k-chunk s^(r&7)).
// Kills the 16-way ds_read_b128 bank conflicts (row stride 128 B == 32 banks
// put all 16 fragment rows in one 4-bank quad; SQ_LDS_BANK_CONFLICT 2.19e7
// == +12 cyc per ds_read). Staging permutes which chunk each lane fetches,
// keeping the wave-uniform-base + lane*16 global_load_lds constraint.
// ---------------------------------------------------------------------------

typedef __bf16 bf16x8 __attribute__((ext_vector_type(8)));
typedef __bf16 bf16x4 __attribute__((ext_vector_type(4)));
typedef float floatx4 __attribute__((ext_vector_type(4)));

__device__ __forceinline__ void async_load16(const void* g, void* l) {
    __builtin_amdgcn_global_load_lds(
        (const __attribute__((address_space(1))) void*)g,
        (__attribute__((address_space(3))) void*)l,
        16, 0, 0);
}

// fp32 -> bf16 conversion, 4 elems/thread
__global__ __launch_bounds__(256) void x_to_bf16(
    const float* __restrict__ in, __hip_bfloat16* __restrict__ out, int n4)
{
    int i = blockIdx.x * 256 + threadIdx.x;
    if (i < n4) {
        float4 v = ((const float4*)in)[i];
        bf16x4 o;
        o[0] = (__bf16)v.x; o[1] = (__bf16)v.y;
        o[2] = (__bf16)v.z; o[3] = (__bf16)v.w;
        ((bf16x4*)out)[i] = o;
    }
}

// One block per row of W[rows, cols] (fp32): alpha[row] = mean|W[row,:]|,
// sgn[row,:] = sign(W) as exact bf16 (+1/-1/0). float4 loads.
__global__ __launch_bounds__(256) void bin_prep(
    const float* __restrict__ w,
    __hip_bfloat16* __restrict__ sgn,
    float* __restrict__ alpha,
    int cols4)  // cols/4
{
    const int row = blockIdx.x;
    const float4* wr = (const float4*)w + (size_t)row * cols4;
    bf16x4* sr = (bf16x4*)sgn + (size_t)row * cols4;
    float s = 0.0f;
    for (int c = threadIdx.x; c < cols4; c += 256) {
        float4 v = wr[c];
        s += fabsf(v.x) + fabsf(v.y) + fabsf(v.z) + fabsf(v.w);
        bf16x4 o;
        o[0] = (__bf16)(v.x > 0.0f ? 1.0f : (v.x < 0.0f ? -1.0f : 0.0f));
        o[1] = (__bf16)(v.y > 0.0f ? 1.0f : (v.y < 0.0f ? -1.0f : 0.0f));
        o[2] = (__bf16)(v.z > 0.0f ? 1.0f : (v.z < 0.0f ? -1.0f : 0.0f));
        o[3] = (__bf16)(v.w > 0.0f ? 1.0f : (v.w < 0.0f ? -1.0f : 0.0f));
        sr[c] = o;
    }
    #pragma unroll
    for (int off = 32; off > 0; off >>= 1) s += __shfl_down(s, off, 64);
    __shared__ float wsum[4];
    const int lane = threadIdx.x & 63;
    const int wv = threadIdx.x >> 6;
    if (lane == 0) wsum[wv] = s;
    __syncthreads();
    if (threadIdx.x == 0) {
        float t = wsum[0] + wsum[1] + wsum[2] + wsum[3];
        alpha[row] = t / (float)(cols4 * 4);
    }
}

#define TILE_M 128
#define TILE_N 128
#define TILE_K 64

__device__ __forceinline__ void store_val(__hip_bfloat16* C, size_t idx, float v) {
    C[idx] = __float2bfloat16(v);
}
__device__ __forceinline__ void store_val(float* C, size_t idx, float v) {
    C[idx] = v;
}

// C[M,N] = (A[M,K] . S[N,K]^T) * alpha[N] + bias[N]  (+ optional gelu/clip)
template <bool DO_GELU, typename OutT>
__global__ __launch_bounds__(256) void gemm_bin(
    const __hip_bfloat16* __restrict__ A,
    const __hip_bfloat16* __restrict__ S,
    const float* __restrict__ alpha,
    const float* __restrict__ bias,
    OutT* __restrict__ C,
    int M, int N, int K)
{
    __shared__ __align__(16) __hip_bfloat16 sA[TILE_M * TILE_K];
    __shared__ __align__(16) __hip_bfloat16 sB[TILE_N * TILE_K];

    const int tid = threadIdx.x;
    const int wave = tid >> 6;
    const int lane = tid & 63;
    const int bm = blockIdx.y * TILE_M;
    const int bn = blockIdx.x * TILE_N;

    // wave -> 64x64 quadrant; lane -> mfma fragment coords
    const int wm = (wave & 1) * 64;
    const int wn = (wave >> 1) * 64;
    const int lr = lane & 15;         // m (A) / n (B) index within 16-tile
    const int kq = lane >> 4;         // 0..3: which 8-elem k-chunk of the 32-step
    const int e3 = lr & 7;            // row parity class for the XOR swizzle

    // staging coords: each lane fetches one 16B chunk (8 bf16).
    // XOR swizzle: LDS slot (lane&7) of row (lane>>3) receives global chunk
    // (lane&7)^(lane>>3), so slot s of row r holds chunk s^r.
    const int crow = lane >> 3;                         // 0..7 row within segment
    const int ccol = (((lane & 7) ^ crow) * 8);         // global element column

    floatx4 acc[4][4];
    #pragma unroll
    for (int i = 0; i < 4; i++)
        #pragma unroll
        for (int j = 0; j < 4; j++)
            #pragma unroll
            for (int r = 0; r < 4; r++)
                acc[i][j][r] = 0.0f;

    for (int k0 = 0; k0 < K; k0 += TILE_K) {
        // --- stage A and B tiles (global -> LDS, 16B/lane, wave-uniform dst)
        #pragma unroll
        for (int j = 0; j < 4; j++) {
            const int seg = wave * 4 + j;        // 0..15, 8 rows each
            const int r = seg * 8 + crow;        // 0..127
            int ar = bm + r;
            ar = ar < M ? ar : (M - 1);          // clamp tail rows (stores guarded)
            async_load16(A + (size_t)ar * K + (k0 + ccol), (void*)(sA + seg * 512));
            async_load16(S + (size_t)(bn + r) * K + (k0 + ccol), (void*)(sB + seg * 512));
        }
        __syncthreads();

        // --- compute: 2 k-steps of 32, 16 MFMAs each
        #pragma unroll
        for (int ks = 0; ks < 2; ks++) {
            // k-chunk index kc = ks*4 + kq; stored in slot kc ^ (row&7).
            const int slot = ((ks << 2) | kq) ^ e3;
            bf16x8 af[4], bfv[4];
            #pragma unroll
            for (int i = 0; i < 4; i++)
                af[i] = *(const bf16x8*)(sA + (wm + i * 16 + lr) * TILE_K + slot * 8);
            #pragma unroll
            for (int j = 0; j < 4; j++)
                bfv[j] = *(const bf16x8*)(sB + (wn + j * 16 + lr) * TILE_K + slot * 8);
            #pragma unroll
            for (int i = 0; i < 4; i++)
                #pragma unroll
                for (int j = 0; j < 4; j++)
                    acc[i][j] = __builtin_amdgcn_mfma_f32_16x16x32_bf16(
                        af[i], bfv[j], acc[i][j], 0, 0, 0);
        }
        __syncthreads();
    }

    // --- epilogue: alpha/bias in fp32, optional exact-erf gelu + clip
    float al[4], bi[4];
    #pragma unroll
    for (int j = 0; j < 4; j++) {
        const int col = bn + wn + j * 16 + lr;
        al[j] = alpha[col];
        bi[j] = bias[col];
    }
    #pragma unroll
    for (int i = 0; i < 4; i++) {
        const int row0 = bm + wm + i * 16 + (lane >> 4) * 4;
        #pragma unroll
        for (int r = 0; r < 4; r++) {
            const int row = row0 + r;
            if (row < M) {
                #pragma unroll
                for (int j = 0; j < 4; j++) {
                    float v = acc[i][j][r] * al[j] + bi[j];
                    if (DO_GELU) {
                        v = 0.5f * v * (1.0f + erff(v * 0.70710678118654752f));
                        v = fminf(fmaxf(v, -10.0f), 10.0f);
                    }
                    store_val(C, (size_t)row * N + (bn + wn + j * 16 + lr), v);
                }
            }
        }
    }
}

extern "C" void kernel_launch(void* const* d_in, const int* in_sizes, int n_in,
                              void* d_out, int out_size, void* d_ws, size_t ws_size,
                              hipStream_t stream) {
    const float* x  = (const float*)d_in[0];
    const float* w1 = (const float*)d_in[1];
    const float* b1 = (const float*)d_in[2];
    const float* w2 = (const float*)d_in[3];
    const float* b2 = (const float*)d_in[4];

    const int M = 64 * 197;   // 12608
    const int Cd = 768;
    const int Hd = 3072;

    // workspace layout (~106 MB total)
    char* ws = (char*)d_ws;
    __hip_bfloat16* xb   = (__hip_bfloat16*)ws;                 // [M, Cd]
    __hip_bfloat16* sgn1 = xb + (size_t)M * Cd;                 // [Hd, Cd]
    __hip_bfloat16* sgn2 = sgn1 + (size_t)Hd * Cd;              // [Cd, Hd]
    float* alpha1 = (float*)(sgn2 + (size_t)Cd * Hd);           // [Hd]
    float* alpha2 = alpha1 + Hd;                                // [Cd]
    __hip_bfloat16* hbuf = (__hip_bfloat16*)(alpha2 + Cd);      // [M, Hd]

    const int n4 = (M * Cd) / 4;
    x_to_bf16<<<(n4 + 255) / 256, 256, 0, stream>>>(x, xb, n4);
    bin_prep<<<Hd, 256, 0, stream>>>(w1, sgn1, alpha1, Cd / 4);
    bin_prep<<<Cd, 256, 0, stream>>>(w2, sgn2, alpha2, Hd / 4);

    const int gm = (M + TILE_M - 1) / TILE_M;  // 99
    gemm_bin<true,  __hip_bfloat16><<<dim3(Hd / TILE_N, gm), 256, 0, stream>>>(
        xb, sgn1, alpha1, b1, hbuf, M, Hd, Cd);
    gemm_bin<false, float><<<dim3(Cd / TILE_N, gm), 256, 0, stream>>>(
        hbuf, sgn2, alpha2, b2, (float*)d_out, M, Cd, Hd);
}